// Round 19
// baseline (506.353 us; speedup 1.0000x reference)
//
#include <hip/hip_runtime.h>

// ---------------------------------------------------------------------------
// A3TGCN2 TemporalGNN, MI355X (gfx950)
//
// Pipeline: memset(deg/cursor), k_deg, k_prep(pack), k_scan(+dinv), k_csr,
//           k_agg, k_gru
//
// R1: 12x unroll -> spill.  R2: launch_bounds VGPR cap -> spill.
// R3: pointer-passed local arrays never promoted -> named vector X-macros.
// R4/R5/R12: macro token-pasting traps (pp-numbers, member params, XCAT).
// R6: global vector weight loads: latency-serialized (496us).
// R7: lane-split weights -> spill. R8: LDS + free scheduling -> spill.
// R9/R13: LDS-only weights: 228us = LDS-pipe instruction-throughput bound.
// R14: 2 nodes/lane -> 0.76 waves/SIMD latency-exposed. REVERTED.
// R15: all-scalar: 304us. R17: uniform global loads scalarized. REVERTED.
// R16: 50/50 LDS ds_read_b128 + s_load_dwordx16 hybrid: 200us.
// R18: k_agg 2 threads/node + col/wgt prefetch: k_agg off the top-5.
// R19: k_gru STEP was LOADS-FIRST: the lgkmcnt(0) before each step's FMAs
//      (forced because ds_read and s_load SHARE lgkmcnt and s_load returns
//      out-of-order) drained the just-issued next-row loads -> full LDS
//      latency exposed per step (430cyc/step measured vs ~140 issue).
//      Fix: FMA-first step [FMA(cur); SBAR; LD(next); SBAR] -- the wait
//      now covers only loads issued a full step earlier (drain ~ free).
// ---------------------------------------------------------------------------

#define NN 50000
#define NE 800000
#define FIN 8
#define PER 12
#define HID 32
#define BATCH 2
#define FP 96                 // FIN*PER
#define BN (BATCH * NN)
#define OUTF 24               // PER*NTF

// packed parameter block (floats): probs | 3x[M|Lbot|c] | Wout | bout
#define OFF_PROBS  0          // 12 (pad to 16)
#define OFF_WPK    16
#define GSTRIDE    1312       // [8x32 M][32x32 Lbot][32 c]; row r at 32*r
#define OFF_WOUT   3952       // 32 x 24 (row-major)
#define OFF_BOUT   4720       // 24
#define SM_TOT     4744       // 18976 B of LDS

// workspace layout (float units)
#define OFF_DINV   4744       // N floats
#define OFF_DEGI   54744      // N ints (contiguous with cursor for memset)
#define OFF_CURSOR 104744     // N ints
#define OFF_ROWPTR 154744     // N+1 ints
#define OFF_COL    204752     // E ints
#define OFF_WGT    1004752    // E floats
#define OFF_AX     1804752    // 96 * B*N floats
#define WS_FLOATS  11404752   // ~45.6 MB needed

__device__ __forceinline__ float fast_exp2(float x) {
#if __has_builtin(__builtin_amdgcn_exp2f)
    return __builtin_amdgcn_exp2f(x);
#else
    return exp2f(x);
#endif
}
__device__ __forceinline__ float fast_rcp(float x) {
#if __has_builtin(__builtin_amdgcn_rcpf)
    return __builtin_amdgcn_rcpf(x);
#else
    return 1.0f / x;
#endif
}
__device__ __forceinline__ float sigm(float x) {
    return fast_rcp(1.0f + fast_exp2(-1.4426950408889634f * x));
}
__device__ __forceinline__ float tanh_fast(float x) {
    return 2.0f * fast_rcp(1.0f + fast_exp2(-2.8853900817779268f * x)) - 1.0f;
}

__global__ void k_deg(const int* __restrict__ dst, int* __restrict__ degi) {
    int e = blockIdx.x * blockDim.x + threadIdx.x;
    if (e < NE) atomicAdd(&degi[dst[e]], 1);
}

// Packs: probs, per-gate [M(8x32) | Lbot(32x32) | c(32)], Wout, bout.
__global__ void k_prep(const float* __restrict__ att,
                       const float* __restrict__ Wz, const float* __restrict__ bz,
                       const float* __restrict__ Wr, const float* __restrict__ br,
                       const float* __restrict__ Wh, const float* __restrict__ bh,
                       const float* __restrict__ Lz, const float* __restrict__ lbz,
                       const float* __restrict__ Lr, const float* __restrict__ lbr,
                       const float* __restrict__ Lh, const float* __restrict__ lbh,
                       const float* __restrict__ Wout, const float* __restrict__ bout,
                       float* __restrict__ ws) {
    int tid = threadIdx.x;
    if (tid == 0) {
        float a[PER], m = -1e30f, s = 0.0f;
        for (int i = 0; i < PER; i++) { a[i] = att[i]; m = fmaxf(m, a[i]); }
        for (int i = 0; i < PER; i++) { a[i] = __expf(a[i] - m); s += a[i]; }
        for (int i = 0; i < PER; i++) ws[OFF_PROBS + i] = a[i] / s;
    }
    int k = tid >> 5, j = tid & 31;   // k in [0,8), j in [0,32)
    const float* Ws[3]  = { Wz, Wr, Wh };
    const float* Ls[3]  = { Lz, Lr, Lh };
    const float* bs[3]  = { bz, br, bh };
    const float* lbs[3] = { lbz, lbr, lbh };
    for (int g = 0; g < 3; g++) {
        float* wp = ws + OFF_WPK + g * GSTRIDE;
        float acc = 0.0f;
        for (int i = 0; i < HID; i++) acc += Ws[g][k * HID + i] * Ls[g][i * HID + j];
        wp[k * HID + j] = acc;
        for (int i = tid; i < 1024; i += 256) wp[256 + i] = Ls[g][1024 + i];
        if (tid < HID) {
            float c = lbs[g][tid];
            for (int i = 0; i < HID; i++) c += bs[g][i] * Ls[g][i * HID + tid];
            wp[1280 + tid] = c;
        }
    }
    for (int i = tid; i < 768; i += 256) ws[OFF_WOUT + i] = Wout[i];
    if (tid < OUTF) ws[OFF_BOUT + tid] = bout[tid];
}

// strip scan: 1024 threads x STRIP elements; also computes dinv. One block.
#define STRIP 49   // ceil(50000/1024)
__global__ __launch_bounds__(1024)
void k_scan(const int* __restrict__ degi, int* __restrict__ rowptr,
            float* __restrict__ dinv) {
    __shared__ int wsum[16];
    int tid = threadIdx.x;
    int lane = tid & 63, wid = tid >> 6;
    int s0 = tid * STRIP;
    int vals[STRIP];
    int sum = 0;
    #pragma unroll
    for (int i = 0; i < STRIP; i++) {
        int idx = s0 + i;
        int d = (idx < NN) ? degi[idx] : 0;
        vals[i] = d;
        sum += d;
        if (idx < NN) dinv[idx] = rsqrtf(1.0f + (float)d);
    }
    int run = sum;
    #pragma unroll
    for (int off = 1; off < 64; off <<= 1) {
        int t = __shfl_up(run, off);
        if (lane >= off) run += t;
    }
    if (lane == 63) wsum[wid] = run;
    __syncthreads();
    if (wid == 0 && lane < 16) {
        int v = wsum[lane];
        #pragma unroll
        for (int off = 1; off < 16; off <<= 1) {
            int t = __shfl_up(v, off);
            if (lane >= off) v += t;
        }
        wsum[lane] = v;
    }
    __syncthreads();
    int base = (wid ? wsum[wid - 1] : 0) + (run - sum);
    if (tid == 0) rowptr[0] = 0;
    #pragma unroll
    for (int i = 0; i < STRIP; i++) {
        int idx = s0 + i;
        if (idx < NN) { base += vals[i]; rowptr[idx + 1] = base; }
    }
}

__global__ void k_csr(const int* __restrict__ src, const int* __restrict__ dst,
                      const int* __restrict__ rowptr, int* __restrict__ cursor,
                      const float* __restrict__ dinv,
                      int* __restrict__ col, float* __restrict__ wgt) {
    int e = blockIdx.x * blockDim.x + threadIdx.x;
    if (e >= NE) return;
    int s = src[e], d = dst[e];
    int pos = atomicAdd(&cursor[d], 1);
    int i = rowptr[d] + pos;
    col[i] = s;
    wgt[i] = dinv[s] * dinv[d];
}

// R18: 2 threads per node, each gathers HALF a row (12 float4 = 192B).
// gridDim.y = 2 batch planes. col/wgt software-pipelined (prefetch i+1).
__global__ __launch_bounds__(256)
void k_agg(const float* __restrict__ x,
           const int* __restrict__ rowptr, const int* __restrict__ col,
           const float* __restrict__ wgt, const float* __restrict__ dinv,
           float* __restrict__ AX) {
    int tid = blockIdx.x * blockDim.x + threadIdx.x;
    int n  = tid >> 1;                    // node
    int hf = tid & 1;                     // half-row: floats [hf*48, hf*48+48)
    if (n >= NN) return;
    const float* xb = x + (size_t)blockIdx.y * (NN * FP) + hf * 48;
    float* axb = AX + (size_t)blockIdx.y * NN + n;   // AX[q*BN + b*NN + n]
    int r0 = rowptr[n], r1 = rowptr[n + 1];

    float4 acc[12];
    #pragma unroll
    for (int c = 0; c < 12; c++) acc[c] = make_float4(0.f, 0.f, 0.f, 0.f);

    if (r0 < r1) {
        int   cs = col[r0];
        float wv = wgt[r0];
        #pragma unroll 1
        for (int i = r0; i < r1; i++) {
            // prefetch next edge's index/weight (clamped; off the chain)
            int nxt = (i + 1 < r1) ? i + 1 : i;
            int   cn = col[nxt];
            float wn = wgt[nxt];
            const float* row = xb + (size_t)cs * FP;
            float4 v[12];
            #pragma unroll
            for (int c = 0; c < 12; c++) v[c] = *(const float4*)(row + c * 4);
            __builtin_amdgcn_sched_barrier(0);   // keep the 12 loads clustered
            #pragma unroll
            for (int c = 0; c < 12; c++) {
                acc[c].x = fmaf(wv, v[c].x, acc[c].x);
                acc[c].y = fmaf(wv, v[c].y, acc[c].y);
                acc[c].z = fmaf(wv, v[c].z, acc[c].z);
                acc[c].w = fmaf(wv, v[c].w, acc[c].w);
            }
            cs = cn; wv = wn;
        }
    }
    {   // self loop: weight dinv[n]^2
        float di = dinv[n];
        float wv = di * di;
        const float* row = xb + (size_t)n * FP;
        float4 v[12];
        #pragma unroll
        for (int c = 0; c < 12; c++) v[c] = *(const float4*)(row + c * 4);
        __builtin_amdgcn_sched_barrier(0);
        #pragma unroll
        for (int c = 0; c < 12; c++) {
            acc[c].x = fmaf(wv, v[c].x, acc[c].x);
            acc[c].y = fmaf(wv, v[c].y, acc[c].y);
            acc[c].z = fmaf(wv, v[c].z, acc[c].z);
            acc[c].w = fmaf(wv, v[c].w, acc[c].w);
        }
    }
    #pragma unroll
    for (int c = 0; c < 12; c++) {
        int q = hf * 48 + c * 4;
        axb[(size_t)(q + 0) * BN] = acc[c].x;
        axb[(size_t)(q + 1) * BN] = acc[c].y;
        axb[(size_t)(q + 2) * BN] = acc[c].z;
        axb[(size_t)(q + 3) * BN] = acc[c].w;
    }
}

// ----- array-free GRU: hybrid LDS + scalar(x16) weights, FMA-first steps -----

// deferred concat: expands macro args BEFORE pasting (R12 lesson)
#define XCAT_(a,b) a##b
#define XCAT(a,b) XCAT_(a,b)

typedef __attribute__((ext_vector_type(4)))  float f4;
typedef __attribute__((ext_vector_type(16))) float f16v;
typedef const f16v __attribute__((address_space(4))) cf16;
typedef const f4   __attribute__((address_space(4))) cf4;
#define CLD16(W, ofs) (*(cf16*)(unsigned long long)((W) + (ofs)))
#define CLD4(W, ofs)  (*(cf4*)(unsigned long long)((W) + (ofs)))

#define FOR32(OP) \
    OP(0,x,0)  OP(0,y,1)  OP(0,z,2)  OP(0,w,3) \
    OP(1,x,4)  OP(1,y,5)  OP(1,z,6)  OP(1,w,7) \
    OP(2,x,8)  OP(2,y,9)  OP(2,z,10) OP(2,w,11) \
    OP(3,x,12) OP(3,y,13) OP(3,z,14) OP(3,w,15) \
    OP(4,x,16) OP(4,y,17) OP(4,z,18) OP(4,w,19) \
    OP(5,x,20) OP(5,y,21) OP(5,z,22) OP(5,w,23) \
    OP(6,x,24) OP(6,y,25) OP(6,z,26) OP(6,w,27) \
    OP(7,x,28) OP(7,y,29) OP(7,z,30) OP(7,w,31)

// component-wise fma; param names must not be x/y/z/w (R5 lesson)
#define FMA4(dd, ss, vv) \
    dd.x = fmaf((ss), (vv).x, dd.x); dd.y = fmaf((ss), (vv).y, dd.y); \
    dd.z = fmaf((ss), (vv).z, dd.z); dd.w = fmaf((ss), (vv).w, dd.w);

// schedule pin (spill preventer / pipeline stepper)
#define SBAR() __builtin_amdgcn_sched_barrier(0)

// LDS row load: 8x ds_read_b128, uniform addr broadcast
#define ROWLD_V(U, W, ofs) \
    XCAT(U,0) = *(const f4*)((W) + (ofs)); \
    XCAT(U,1) = *(const f4*)((W) + (ofs) + 4); \
    XCAT(U,2) = *(const f4*)((W) + (ofs) + 8); \
    XCAT(U,3) = *(const f4*)((W) + (ofs) + 12); \
    XCAT(U,4) = *(const f4*)((W) + (ofs) + 16); \
    XCAT(U,5) = *(const f4*)((W) + (ofs) + 20); \
    XCAT(U,6) = *(const f4*)((W) + (ofs) + 24); \
    XCAT(U,7) = *(const f4*)((W) + (ofs) + 28);

// constant row load: 2x s_load_dwordx16 into SGPRs
#define ROWLD_S(S, W, ofs) \
    XCAT(S,L) = CLD16(W, (ofs)); \
    XCAT(S,H) = CLD16(W, (ofs) + 16);

#define ROWFMA_V(P, a, U) do { \
    float av = (a); \
    FMA4(XCAT(P,0), av, XCAT(U,0)) FMA4(XCAT(P,1), av, XCAT(U,1)) \
    FMA4(XCAT(P,2), av, XCAT(U,2)) FMA4(XCAT(P,3), av, XCAT(U,3)) \
    FMA4(XCAT(P,4), av, XCAT(U,4)) FMA4(XCAT(P,5), av, XCAT(U,5)) \
    FMA4(XCAT(P,6), av, XCAT(U,6)) FMA4(XCAT(P,7), av, XCAT(U,7)) \
} while (0)

#define ROWFMA_S(P, a, S) do { \
    float av = (a); \
    XCAT(P,0).x = fmaf(av, XCAT(S,L).s0, XCAT(P,0).x); \
    XCAT(P,0).y = fmaf(av, XCAT(S,L).s1, XCAT(P,0).y); \
    XCAT(P,0).z = fmaf(av, XCAT(S,L).s2, XCAT(P,0).z); \
    XCAT(P,0).w = fmaf(av, XCAT(S,L).s3, XCAT(P,0).w); \
    XCAT(P,1).x = fmaf(av, XCAT(S,L).s4, XCAT(P,1).x); \
    XCAT(P,1).y = fmaf(av, XCAT(S,L).s5, XCAT(P,1).y); \
    XCAT(P,1).z = fmaf(av, XCAT(S,L).s6, XCAT(P,1).z); \
    XCAT(P,1).w = fmaf(av, XCAT(S,L).s7, XCAT(P,1).w); \
    XCAT(P,2).x = fmaf(av, XCAT(S,L).s8, XCAT(P,2).x); \
    XCAT(P,2).y = fmaf(av, XCAT(S,L).s9, XCAT(P,2).y); \
    XCAT(P,2).z = fmaf(av, XCAT(S,L).sa, XCAT(P,2).z); \
    XCAT(P,2).w = fmaf(av, XCAT(S,L).sb, XCAT(P,2).w); \
    XCAT(P,3).x = fmaf(av, XCAT(S,L).sc, XCAT(P,3).x); \
    XCAT(P,3).y = fmaf(av, XCAT(S,L).sd, XCAT(P,3).y); \
    XCAT(P,3).z = fmaf(av, XCAT(S,L).se, XCAT(P,3).z); \
    XCAT(P,3).w = fmaf(av, XCAT(S,L).sf, XCAT(P,3).w); \
    XCAT(P,4).x = fmaf(av, XCAT(S,H).s0, XCAT(P,4).x); \
    XCAT(P,4).y = fmaf(av, XCAT(S,H).s1, XCAT(P,4).y); \
    XCAT(P,4).z = fmaf(av, XCAT(S,H).s2, XCAT(P,4).z); \
    XCAT(P,4).w = fmaf(av, XCAT(S,H).s3, XCAT(P,4).w); \
    XCAT(P,5).x = fmaf(av, XCAT(S,H).s4, XCAT(P,5).x); \
    XCAT(P,5).y = fmaf(av, XCAT(S,H).s5, XCAT(P,5).y); \
    XCAT(P,5).z = fmaf(av, XCAT(S,H).s6, XCAT(P,5).z); \
    XCAT(P,5).w = fmaf(av, XCAT(S,H).s7, XCAT(P,5).w); \
    XCAT(P,6).x = fmaf(av, XCAT(S,H).s8, XCAT(P,6).x); \
    XCAT(P,6).y = fmaf(av, XCAT(S,H).s9, XCAT(P,6).y); \
    XCAT(P,6).z = fmaf(av, XCAT(S,H).sa, XCAT(P,6).z); \
    XCAT(P,6).w = fmaf(av, XCAT(S,H).sb, XCAT(P,6).w); \
    XCAT(P,7).x = fmaf(av, XCAT(S,H).sc, XCAT(P,7).x); \
    XCAT(P,7).y = fmaf(av, XCAT(S,H).sd, XCAT(P,7).y); \
    XCAT(P,7).z = fmaf(av, XCAT(S,H).se, XCAT(P,7).z); \
    XCAT(P,7).w = fmaf(av, XCAT(S,H).sf, XCAT(P,7).w); \
} while (0)

// bias init from LDS (once per gate)
#define LDB(P, W) \
    XCAT(P,0) = *(const f4*)((W) + 1280); XCAT(P,1) = *(const f4*)((W) + 1284); \
    XCAT(P,2) = *(const f4*)((W) + 1288); XCAT(P,3) = *(const f4*)((W) + 1292); \
    XCAT(P,4) = *(const f4*)((W) + 1296); XCAT(P,5) = *(const f4*)((W) + 1300); \
    XCAT(P,6) = *(const f4*)((W) + 1304); XCAT(P,7) = *(const f4*)((W) + 1308);

// R19 FMA-FIRST step: consume rows 2n,2n+1 (loaded one step ago), THEN
// load rows 2n+2/2n+3 into the buffers consumed last step. The inner SBAR
// forbids hoisting loads above the FMAs, so the lgkmcnt wait before the
// FMAs covers only loads issued a full step (~150cyc) earlier.
// Step 19 loads rows 40/41 (bias / next block) -- valid memory, unused.
#define STEP(n, P1,i1,c1, P2,i2,c2, CURV,CURS, NXTV,NXTS) \
    ROWFMA_V(GP, XCAT(P1,i1).c1, CURV); \
    ROWFMA_S(GP, XCAT(P2,i2).c2, CURS); \
    SBAR(); \
    ROWLD_V(NXTV, WgL, 32*(2*(n)+2)); \
    ROWLD_S(NXTS, WgC, 32*(2*(n)+3)); \
    SBAR();

#define FOR20(OP) \
    OP(0,  in,0,x, in,0,y, va,sa, vb,sb) \
    OP(1,  in,0,z, in,0,w, vb,sb, va,sa) \
    OP(2,  in,1,x, in,1,y, va,sa, vb,sb) \
    OP(3,  in,1,z, in,1,w, vb,sb, va,sa) \
    OP(4,  GS,0,x, GS,0,y, va,sa, vb,sb) \
    OP(5,  GS,0,z, GS,0,w, vb,sb, va,sa) \
    OP(6,  GS,1,x, GS,1,y, va,sa, vb,sb) \
    OP(7,  GS,1,z, GS,1,w, vb,sb, va,sa) \
    OP(8,  GS,2,x, GS,2,y, va,sa, vb,sb) \
    OP(9,  GS,2,z, GS,2,w, vb,sb, va,sa) \
    OP(10, GS,3,x, GS,3,y, va,sa, vb,sb) \
    OP(11, GS,3,z, GS,3,w, vb,sb, va,sa) \
    OP(12, GS,4,x, GS,4,y, va,sa, vb,sb) \
    OP(13, GS,4,z, GS,4,w, vb,sb, va,sa) \
    OP(14, GS,5,x, GS,5,y, va,sa, vb,sb) \
    OP(15, GS,5,z, GS,5,w, vb,sb, va,sa) \
    OP(16, GS,6,x, GS,6,y, va,sa, vb,sb) \
    OP(17, GS,6,z, GS,6,w, vb,sb, va,sa) \
    OP(18, GS,7,x, GS,7,y, va,sa, vb,sb) \
    OP(19, GS,7,z, GS,7,w, vb,sb, va,sa)

#define GATE_PIPE() \
    LDB(GP, WgL); ROWLD_V(va, WgL, 0); ROWLD_S(sa, WgC, 32); SBAR(); \
    ROWLD_V(vb, WgL, 64); ROWLD_S(sb, WgC, 96); SBAR(); \
    FOR20(STEP)

#define ZERO_OP(i,c,n) h##i.c = 0.0f; ac##i.c = 0.0f;
#define HR_OP(i,c,n)   o##i.c = sigm(o##i.c) * h##i.c;
#define TANH_OP(i,c,n) t##i.c = tanh_fast(t##i.c);
#define UPD_OP(i,c,n)  { float Zv = sigm(o##i.c); \
                         h##i.c = fmaf(Zv, h##i.c - t##i.c, t##i.c); \
                         ac##i.c = fmaf(pp, h##i.c, ac##i.c); }

#define OROW(a, ofs) do { \
    f4 u0 = CLD4(WO, (ofs)); \
    f4 u1 = CLD4(WO, (ofs) + 4); \
    f4 u2 = CLD4(WO, (ofs) + 8); \
    f4 u3 = CLD4(WO, (ofs) + 12); \
    f4 u4 = CLD4(WO, (ofs) + 16); \
    f4 u5 = CLD4(WO, (ofs) + 20); \
    float av = (a); \
    FMA4(q0, av, u0) FMA4(q1, av, u1) FMA4(q2, av, u2) \
    FMA4(q3, av, u3) FMA4(q4, av, u4) FMA4(q5, av, u5) \
    SBAR(); \
} while (0)

#define OUT_OP(i,c,n) OROW(fmaxf(ac##i.c, 0.0f), (n) * OUTF);

__global__ __launch_bounds__(64)
void k_gru(const float* __restrict__ AX, const float* __restrict__ wp,
           float* __restrict__ out) {
    __shared__ __align__(16) float sm[SM_TOT];
    int tid = threadIdx.x;
    // stage all packed params into LDS once (loop-invariant across periods)
    for (int i = tid; i < SM_TOT; i += 64) sm[i] = wp[i];
    __syncthreads();

    int g = blockIdx.x * 64 + tid;   // g = b*N + n
    if (g >= BN) return;

    f4 h0, h1, h2, h3, h4, h5, h6, h7;
    f4 ac0, ac1, ac2, ac3, ac4, ac5, ac6, ac7;
    f4 o0, o1, o2, o3, o4, o5, o6, o7;
    f4 t0, t1, t2, t3, t4, t5, t6, t7;
    f4 va0, va1, va2, va3, va4, va5, va6, va7;
    f4 vb0, vb1, vb2, vb3, vb4, vb5, vb6, vb7;
    f16v saL, saH, sbL, sbH;
    f4 in0, in1;
    FOR32(ZERO_OP)

    #pragma unroll 1
    for (int p = 0; p < PER; p++) {
        const float* axp = AX + (size_t)p * BN + g;
        in0.x = axp[0];
        in0.y = axp[(size_t)1 * PER * BN];
        in0.z = axp[(size_t)2 * PER * BN];
        in0.w = axp[(size_t)3 * PER * BN];
        in1.x = axp[(size_t)4 * PER * BN];
        in1.y = axp[(size_t)5 * PER * BN];
        in1.z = axp[(size_t)6 * PER * BN];
        in1.w = axp[(size_t)7 * PER * BN];
        float pp = sm[OFF_PROBS + p];

        // R gate: o = bias + M_r in + L_r H  (source h, target o)
        #define GP o
        #define GS h
        { const float* WgL = sm + OFF_WPK + GSTRIDE;
          const float* WgC = wp + OFF_WPK + GSTRIDE;
          GATE_PIPE() }
        #undef GP
        #undef GS
        FOR32(HR_OP)                      // o = sigm(o) * h

        // T gate: t = bias + M_h in + L_h (H*R)  (source o, target t)
        #define GP t
        #define GS o
        { const float* WgL = sm + OFF_WPK + 2 * GSTRIDE;
          const float* WgC = wp + OFF_WPK + 2 * GSTRIDE;
          GATE_PIPE() }
        #undef GP
        #undef GS
        FOR32(TANH_OP)

        // Z gate: o = bias + M_z in + L_z H  (source h, target o)
        #define GP o
        #define GS h
        { const float* WgL = sm + OFF_WPK;
          const float* WgC = wp + OFF_WPK;
          GATE_PIPE() }
        #undef GP
        #undef GS
        FOR32(UPD_OP)
    }

    // epilogue: relu(acc) @ Wout + bout  (constant-space, runs once)
    const float* WO = wp + OFF_WOUT;
    f4 q0 = CLD4(wp, OFF_BOUT + 0);
    f4 q1 = CLD4(wp, OFF_BOUT + 4);
    f4 q2 = CLD4(wp, OFF_BOUT + 8);
    f4 q3 = CLD4(wp, OFF_BOUT + 12);
    f4 q4 = CLD4(wp, OFF_BOUT + 16);
    f4 q5 = CLD4(wp, OFF_BOUT + 20);
    FOR32(OUT_OP)

    float* op = out + (size_t)g * OUTF;
    *(f4*)(op + 0)  = q0; *(f4*)(op + 4)  = q1;
    *(f4*)(op + 8)  = q2; *(f4*)(op + 12) = q3;
    *(f4*)(op + 16) = q4; *(f4*)(op + 20) = q5;
}

extern "C" void kernel_launch(void* const* d_in, const int* in_sizes, int n_in,
                              void* d_out, int out_size, void* d_ws, size_t ws_size,
                              hipStream_t stream) {
    if (ws_size < (size_t)WS_FLOATS * sizeof(float)) return;  // need ~45.6 MB scratch

    const float* x    = (const float*)d_in[0];
    const int*   ei   = (const int*)d_in[1];
    const float* att  = (const float*)d_in[2];
    const float* Wz   = (const float*)d_in[3];
    const float* bz   = (const float*)d_in[4];
    const float* Wr   = (const float*)d_in[5];
    const float* br   = (const float*)d_in[6];
    const float* Wh   = (const float*)d_in[7];
    const float* bh   = (const float*)d_in[8];
    const float* Lz   = (const float*)d_in[9];
    const float* lbz  = (const float*)d_in[10];
    const float* Lr   = (const float*)d_in[11];
    const float* lbr  = (const float*)d_in[12];
    const float* Lh   = (const float*)d_in[13];
    const float* lbh  = (const float*)d_in[14];
    const float* Wout = (const float*)d_in[15];
    const float* bout = (const float*)d_in[16];
    float* out = (float*)d_out;
    float* ws  = (float*)d_ws;

    const int* src = ei;
    const int* dst = ei + NE;

    float* dinv   = ws + OFF_DINV;
    int*   degi   = (int*)(ws + OFF_DEGI);
    int*   cursor = (int*)(ws + OFF_CURSOR);
    int*   rowptr = (int*)(ws + OFF_ROWPTR);
    int*   col    = (int*)(ws + OFF_COL);
    float* wgt    = ws + OFF_WGT;
    float* AX     = ws + OFF_AX;

    hipMemsetAsync(degi, 0, 2 * (size_t)NN * sizeof(int), stream);
    k_deg<<<(NE + 255) / 256, 256, 0, stream>>>(dst, degi);
    k_prep<<<1, 256, 0, stream>>>(att, Wz, bz, Wr, br, Wh, bh,
                                  Lz, lbz, Lr, lbr, Lh, lbh, Wout, bout, ws);
    k_scan<<<1, 1024, 0, stream>>>(degi, rowptr, dinv);
    k_csr<<<(NE + 255) / 256, 256, 0, stream>>>(src, dst, rowptr, cursor, dinv, col, wgt);
    dim3 gAgg((2 * NN + 255) / 256, 2);
    k_agg<<<gAgg, 256, 0, stream>>>(x, rowptr, col, wgt, dinv, AX);
    k_gru<<<(BN + 63) / 64, 64, 0, stream>>>(AX, ws, out);
}

// Round 20
// 489.609 us; speedup vs baseline: 1.0342x; 1.0342x over previous
//
#include <hip/hip_runtime.h>

// ---------------------------------------------------------------------------
// A3TGCN2 TemporalGNN, MI355X (gfx950)
//
// Pipeline: memset(deg/cursor), k_deg, k_prep(pack), k_scan(+dinv), k_csr,
//           k_agg, k_gru
//
// R1: 12x unroll -> spill.  R2: launch_bounds VGPR cap -> spill.
// R3: pointer-passed local arrays never promoted -> named vector X-macros.
// R4/R5/R12: macro token-pasting traps (pp-numbers, member params, XCAT).
// R6: global vector weight loads: latency-serialized (496us).
// R7: lane-split weights -> spill. R8: LDS + free scheduling -> spill.
// R9/R13: LDS-only weights: 228us = LDS-pipe instruction-throughput bound.
// R14: 2 nodes/lane -> 0.76 waves/SIMD latency-exposed. REVERTED.
// R15: all-scalar: 304us. R17: uniform global loads scalarized. REVERTED.
// R16: 50/50 LDS ds_read_b128 + s_load_dwordx16 hybrid, LOADS-FIRST step:
//      198us (load->use gap ~130cyc = the step's own FMAs).
// R18: k_agg 2 threads/node + col/wgt prefetch: k_agg off the top-5.
// R19: FMA-first but loaded rows 2n+2/2n+3 into the OTHER buffer -> gap
//      collapsed to ~0 -> 211us. WRONG BUFFER TARGET.
// R20: FMA-first + reload the JUST-CONSUMED buffer with rows 2n+4/2n+5:
//      distance-2 with only 2 buffers; load->use gap ~270cyc covers LDS
//      (~120-170cyc) and K$ latency. One-macro fix on the R18 baseline.
// ---------------------------------------------------------------------------

#define NN 50000
#define NE 800000
#define FIN 8
#define PER 12
#define HID 32
#define BATCH 2
#define FP 96                 // FIN*PER
#define BN (BATCH * NN)
#define OUTF 24               // PER*NTF

// packed parameter block (floats): probs | 3x[M|Lbot|c] | Wout | bout
#define OFF_PROBS  0          // 12 (pad to 16)
#define OFF_WPK    16
#define GSTRIDE    1312       // [8x32 M][32x32 Lbot][32 c]; row r at 32*r
#define OFF_WOUT   3952       // 32 x 24 (row-major)
#define OFF_BOUT   4720       // 24
#define SM_TOT     4744       // 18976 B of LDS

// workspace layout (float units)
#define OFF_DINV   4744       // N floats
#define OFF_DEGI   54744      // N ints (contiguous with cursor for memset)
#define OFF_CURSOR 104744     // N ints
#define OFF_ROWPTR 154744     // N+1 ints
#define OFF_COL    204752     // E ints
#define OFF_WGT    1004752    // E floats
#define OFF_AX     1804752    // 96 * B*N floats
#define WS_FLOATS  11404752   // ~45.6 MB needed

__device__ __forceinline__ float fast_exp2(float x) {
#if __has_builtin(__builtin_amdgcn_exp2f)
    return __builtin_amdgcn_exp2f(x);
#else
    return exp2f(x);
#endif
}
__device__ __forceinline__ float fast_rcp(float x) {
#if __has_builtin(__builtin_amdgcn_rcpf)
    return __builtin_amdgcn_rcpf(x);
#else
    return 1.0f / x;
#endif
}
__device__ __forceinline__ float sigm(float x) {
    return fast_rcp(1.0f + fast_exp2(-1.4426950408889634f * x));
}
__device__ __forceinline__ float tanh_fast(float x) {
    return 2.0f * fast_rcp(1.0f + fast_exp2(-2.8853900817779268f * x)) - 1.0f;
}

__global__ void k_deg(const int* __restrict__ dst, int* __restrict__ degi) {
    int e = blockIdx.x * blockDim.x + threadIdx.x;
    if (e < NE) atomicAdd(&degi[dst[e]], 1);
}

// Packs: probs, per-gate [M(8x32) | Lbot(32x32) | c(32)], Wout, bout.
__global__ void k_prep(const float* __restrict__ att,
                       const float* __restrict__ Wz, const float* __restrict__ bz,
                       const float* __restrict__ Wr, const float* __restrict__ br,
                       const float* __restrict__ Wh, const float* __restrict__ bh,
                       const float* __restrict__ Lz, const float* __restrict__ lbz,
                       const float* __restrict__ Lr, const float* __restrict__ lbr,
                       const float* __restrict__ Lh, const float* __restrict__ lbh,
                       const float* __restrict__ Wout, const float* __restrict__ bout,
                       float* __restrict__ ws) {
    int tid = threadIdx.x;
    if (tid == 0) {
        float a[PER], m = -1e30f, s = 0.0f;
        for (int i = 0; i < PER; i++) { a[i] = att[i]; m = fmaxf(m, a[i]); }
        for (int i = 0; i < PER; i++) { a[i] = __expf(a[i] - m); s += a[i]; }
        for (int i = 0; i < PER; i++) ws[OFF_PROBS + i] = a[i] / s;
    }
    int k = tid >> 5, j = tid & 31;   // k in [0,8), j in [0,32)
    const float* Ws[3]  = { Wz, Wr, Wh };
    const float* Ls[3]  = { Lz, Lr, Lh };
    const float* bs[3]  = { bz, br, bh };
    const float* lbs[3] = { lbz, lbr, lbh };
    for (int g = 0; g < 3; g++) {
        float* wp = ws + OFF_WPK + g * GSTRIDE;
        float acc = 0.0f;
        for (int i = 0; i < HID; i++) acc += Ws[g][k * HID + i] * Ls[g][i * HID + j];
        wp[k * HID + j] = acc;
        for (int i = tid; i < 1024; i += 256) wp[256 + i] = Ls[g][1024 + i];
        if (tid < HID) {
            float c = lbs[g][tid];
            for (int i = 0; i < HID; i++) c += bs[g][i] * Ls[g][i * HID + tid];
            wp[1280 + tid] = c;
        }
    }
    for (int i = tid; i < 768; i += 256) ws[OFF_WOUT + i] = Wout[i];
    if (tid < OUTF) ws[OFF_BOUT + tid] = bout[tid];
}

// strip scan: 1024 threads x STRIP elements; also computes dinv. One block.
#define STRIP 49   // ceil(50000/1024)
__global__ __launch_bounds__(1024)
void k_scan(const int* __restrict__ degi, int* __restrict__ rowptr,
            float* __restrict__ dinv) {
    __shared__ int wsum[16];
    int tid = threadIdx.x;
    int lane = tid & 63, wid = tid >> 6;
    int s0 = tid * STRIP;
    int vals[STRIP];
    int sum = 0;
    #pragma unroll
    for (int i = 0; i < STRIP; i++) {
        int idx = s0 + i;
        int d = (idx < NN) ? degi[idx] : 0;
        vals[i] = d;
        sum += d;
        if (idx < NN) dinv[idx] = rsqrtf(1.0f + (float)d);
    }
    int run = sum;
    #pragma unroll
    for (int off = 1; off < 64; off <<= 1) {
        int t = __shfl_up(run, off);
        if (lane >= off) run += t;
    }
    if (lane == 63) wsum[wid] = run;
    __syncthreads();
    if (wid == 0 && lane < 16) {
        int v = wsum[lane];
        #pragma unroll
        for (int off = 1; off < 16; off <<= 1) {
            int t = __shfl_up(v, off);
            if (lane >= off) v += t;
        }
        wsum[lane] = v;
    }
    __syncthreads();
    int base = (wid ? wsum[wid - 1] : 0) + (run - sum);
    if (tid == 0) rowptr[0] = 0;
    #pragma unroll
    for (int i = 0; i < STRIP; i++) {
        int idx = s0 + i;
        if (idx < NN) { base += vals[i]; rowptr[idx + 1] = base; }
    }
}

__global__ void k_csr(const int* __restrict__ src, const int* __restrict__ dst,
                      const int* __restrict__ rowptr, int* __restrict__ cursor,
                      const float* __restrict__ dinv,
                      int* __restrict__ col, float* __restrict__ wgt) {
    int e = blockIdx.x * blockDim.x + threadIdx.x;
    if (e >= NE) return;
    int s = src[e], d = dst[e];
    int pos = atomicAdd(&cursor[d], 1);
    int i = rowptr[d] + pos;
    col[i] = s;
    wgt[i] = dinv[s] * dinv[d];
}

// R18: 2 threads per node, each gathers HALF a row (12 float4 = 192B).
// gridDim.y = 2 batch planes. col/wgt software-pipelined (prefetch i+1).
__global__ __launch_bounds__(256)
void k_agg(const float* __restrict__ x,
           const int* __restrict__ rowptr, const int* __restrict__ col,
           const float* __restrict__ wgt, const float* __restrict__ dinv,
           float* __restrict__ AX) {
    int tid = blockIdx.x * blockDim.x + threadIdx.x;
    int n  = tid >> 1;                    // node
    int hf = tid & 1;                     // half-row: floats [hf*48, hf*48+48)
    if (n >= NN) return;
    const float* xb = x + (size_t)blockIdx.y * (NN * FP) + hf * 48;
    float* axb = AX + (size_t)blockIdx.y * NN + n;   // AX[q*BN + b*NN + n]
    int r0 = rowptr[n], r1 = rowptr[n + 1];

    float4 acc[12];
    #pragma unroll
    for (int c = 0; c < 12; c++) acc[c] = make_float4(0.f, 0.f, 0.f, 0.f);

    if (r0 < r1) {
        int   cs = col[r0];
        float wv = wgt[r0];
        #pragma unroll 1
        for (int i = r0; i < r1; i++) {
            // prefetch next edge's index/weight (clamped; off the chain)
            int nxt = (i + 1 < r1) ? i + 1 : i;
            int   cn = col[nxt];
            float wn = wgt[nxt];
            const float* row = xb + (size_t)cs * FP;
            float4 v[12];
            #pragma unroll
            for (int c = 0; c < 12; c++) v[c] = *(const float4*)(row + c * 4);
            __builtin_amdgcn_sched_barrier(0);   // keep the 12 loads clustered
            #pragma unroll
            for (int c = 0; c < 12; c++) {
                acc[c].x = fmaf(wv, v[c].x, acc[c].x);
                acc[c].y = fmaf(wv, v[c].y, acc[c].y);
                acc[c].z = fmaf(wv, v[c].z, acc[c].z);
                acc[c].w = fmaf(wv, v[c].w, acc[c].w);
            }
            cs = cn; wv = wn;
        }
    }
    {   // self loop: weight dinv[n]^2
        float di = dinv[n];
        float wv = di * di;
        const float* row = xb + (size_t)n * FP;
        float4 v[12];
        #pragma unroll
        for (int c = 0; c < 12; c++) v[c] = *(const float4*)(row + c * 4);
        __builtin_amdgcn_sched_barrier(0);
        #pragma unroll
        for (int c = 0; c < 12; c++) {
            acc[c].x = fmaf(wv, v[c].x, acc[c].x);
            acc[c].y = fmaf(wv, v[c].y, acc[c].y);
            acc[c].z = fmaf(wv, v[c].z, acc[c].z);
            acc[c].w = fmaf(wv, v[c].w, acc[c].w);
        }
    }
    #pragma unroll
    for (int c = 0; c < 12; c++) {
        int q = hf * 48 + c * 4;
        axb[(size_t)(q + 0) * BN] = acc[c].x;
        axb[(size_t)(q + 1) * BN] = acc[c].y;
        axb[(size_t)(q + 2) * BN] = acc[c].z;
        axb[(size_t)(q + 3) * BN] = acc[c].w;
    }
}

// ----- array-free GRU: hybrid LDS + scalar(x16), distance-2 pipeline -----

// deferred concat: expands macro args BEFORE pasting (R12 lesson)
#define XCAT_(a,b) a##b
#define XCAT(a,b) XCAT_(a,b)

typedef __attribute__((ext_vector_type(4)))  float f4;
typedef __attribute__((ext_vector_type(16))) float f16v;
typedef const f16v __attribute__((address_space(4))) cf16;
typedef const f4   __attribute__((address_space(4))) cf4;
#define CLD16(W, ofs) (*(cf16*)(unsigned long long)((W) + (ofs)))
#define CLD4(W, ofs)  (*(cf4*)(unsigned long long)((W) + (ofs)))

#define FOR32(OP) \
    OP(0,x,0)  OP(0,y,1)  OP(0,z,2)  OP(0,w,3) \
    OP(1,x,4)  OP(1,y,5)  OP(1,z,6)  OP(1,w,7) \
    OP(2,x,8)  OP(2,y,9)  OP(2,z,10) OP(2,w,11) \
    OP(3,x,12) OP(3,y,13) OP(3,z,14) OP(3,w,15) \
    OP(4,x,16) OP(4,y,17) OP(4,z,18) OP(4,w,19) \
    OP(5,x,20) OP(5,y,21) OP(5,z,22) OP(5,w,23) \
    OP(6,x,24) OP(6,y,25) OP(6,z,26) OP(6,w,27) \
    OP(7,x,28) OP(7,y,29) OP(7,z,30) OP(7,w,31)

// component-wise fma; param names must not be x/y/z/w (R5 lesson)
#define FMA4(dd, ss, vv) \
    dd.x = fmaf((ss), (vv).x, dd.x); dd.y = fmaf((ss), (vv).y, dd.y); \
    dd.z = fmaf((ss), (vv).z, dd.z); dd.w = fmaf((ss), (vv).w, dd.w);

// schedule pin (spill preventer / pipeline stepper)
#define SBAR() __builtin_amdgcn_sched_barrier(0)

// LDS row load: 8x ds_read_b128, uniform addr broadcast
#define ROWLD_V(U, W, ofs) \
    XCAT(U,0) = *(const f4*)((W) + (ofs)); \
    XCAT(U,1) = *(const f4*)((W) + (ofs) + 4); \
    XCAT(U,2) = *(const f4*)((W) + (ofs) + 8); \
    XCAT(U,3) = *(const f4*)((W) + (ofs) + 12); \
    XCAT(U,4) = *(const f4*)((W) + (ofs) + 16); \
    XCAT(U,5) = *(const f4*)((W) + (ofs) + 20); \
    XCAT(U,6) = *(const f4*)((W) + (ofs) + 24); \
    XCAT(U,7) = *(const f4*)((W) + (ofs) + 28);

// constant row load: 2x s_load_dwordx16 into SGPRs
#define ROWLD_S(S, W, ofs) \
    XCAT(S,L) = CLD16(W, (ofs)); \
    XCAT(S,H) = CLD16(W, (ofs) + 16);

#define ROWFMA_V(P, a, U) do { \
    float av = (a); \
    FMA4(XCAT(P,0), av, XCAT(U,0)) FMA4(XCAT(P,1), av, XCAT(U,1)) \
    FMA4(XCAT(P,2), av, XCAT(U,2)) FMA4(XCAT(P,3), av, XCAT(U,3)) \
    FMA4(XCAT(P,4), av, XCAT(U,4)) FMA4(XCAT(P,5), av, XCAT(U,5)) \
    FMA4(XCAT(P,6), av, XCAT(U,6)) FMA4(XCAT(P,7), av, XCAT(U,7)) \
} while (0)

#define ROWFMA_S(P, a, S) do { \
    float av = (a); \
    XCAT(P,0).x = fmaf(av, XCAT(S,L).s0, XCAT(P,0).x); \
    XCAT(P,0).y = fmaf(av, XCAT(S,L).s1, XCAT(P,0).y); \
    XCAT(P,0).z = fmaf(av, XCAT(S,L).s2, XCAT(P,0).z); \
    XCAT(P,0).w = fmaf(av, XCAT(S,L).s3, XCAT(P,0).w); \
    XCAT(P,1).x = fmaf(av, XCAT(S,L).s4, XCAT(P,1).x); \
    XCAT(P,1).y = fmaf(av, XCAT(S,L).s5, XCAT(P,1).y); \
    XCAT(P,1).z = fmaf(av, XCAT(S,L).s6, XCAT(P,1).z); \
    XCAT(P,1).w = fmaf(av, XCAT(S,L).s7, XCAT(P,1).w); \
    XCAT(P,2).x = fmaf(av, XCAT(S,L).s8, XCAT(P,2).x); \
    XCAT(P,2).y = fmaf(av, XCAT(S,L).s9, XCAT(P,2).y); \
    XCAT(P,2).z = fmaf(av, XCAT(S,L).sa, XCAT(P,2).z); \
    XCAT(P,2).w = fmaf(av, XCAT(S,L).sb, XCAT(P,2).w); \
    XCAT(P,3).x = fmaf(av, XCAT(S,L).sc, XCAT(P,3).x); \
    XCAT(P,3).y = fmaf(av, XCAT(S,L).sd, XCAT(P,3).y); \
    XCAT(P,3).z = fmaf(av, XCAT(S,L).se, XCAT(P,3).z); \
    XCAT(P,3).w = fmaf(av, XCAT(S,L).sf, XCAT(P,3).w); \
    XCAT(P,4).x = fmaf(av, XCAT(S,H).s0, XCAT(P,4).x); \
    XCAT(P,4).y = fmaf(av, XCAT(S,H).s1, XCAT(P,4).y); \
    XCAT(P,4).z = fmaf(av, XCAT(S,H).s2, XCAT(P,4).z); \
    XCAT(P,4).w = fmaf(av, XCAT(S,H).s3, XCAT(P,4).w); \
    XCAT(P,5).x = fmaf(av, XCAT(S,H).s4, XCAT(P,5).x); \
    XCAT(P,5).y = fmaf(av, XCAT(S,H).s5, XCAT(P,5).y); \
    XCAT(P,5).z = fmaf(av, XCAT(S,H).s6, XCAT(P,5).z); \
    XCAT(P,5).w = fmaf(av, XCAT(S,H).s7, XCAT(P,5).w); \
    XCAT(P,6).x = fmaf(av, XCAT(S,H).s8, XCAT(P,6).x); \
    XCAT(P,6).y = fmaf(av, XCAT(S,H).s9, XCAT(P,6).y); \
    XCAT(P,6).z = fmaf(av, XCAT(S,H).sa, XCAT(P,6).z); \
    XCAT(P,6).w = fmaf(av, XCAT(S,H).sb, XCAT(P,6).w); \
    XCAT(P,7).x = fmaf(av, XCAT(S,H).sc, XCAT(P,7).x); \
    XCAT(P,7).y = fmaf(av, XCAT(S,H).sd, XCAT(P,7).y); \
    XCAT(P,7).z = fmaf(av, XCAT(S,H).se, XCAT(P,7).z); \
    XCAT(P,7).w = fmaf(av, XCAT(S,H).sf, XCAT(P,7).w); \
} while (0)

// bias init from LDS (once per gate)
#define LDB(P, W) \
    XCAT(P,0) = *(const f4*)((W) + 1280); XCAT(P,1) = *(const f4*)((W) + 1284); \
    XCAT(P,2) = *(const f4*)((W) + 1288); XCAT(P,3) = *(const f4*)((W) + 1292); \
    XCAT(P,4) = *(const f4*)((W) + 1296); XCAT(P,5) = *(const f4*)((W) + 1300); \
    XCAT(P,6) = *(const f4*)((W) + 1304); XCAT(P,7) = *(const f4*)((W) + 1308);

// R20 distance-2 step: consume rows 2n (LDS) / 2n+1 (scalar) from the
// buffers loaded TWO steps ago, then reload the SAME buffers with rows
// 2n+4 / 2n+5 (consumed at step n+2). Load->use gap ~270cyc covers LDS
// and K$ latency. Steps 18/19 load rows 40..43 -- valid memory, unused.
#define STEP(n, P1,i1,c1, P2,i2,c2, CURV,CURS) \
    ROWFMA_V(GP, XCAT(P1,i1).c1, CURV); \
    ROWFMA_S(GP, XCAT(P2,i2).c2, CURS); \
    SBAR(); \
    ROWLD_V(CURV, WgL, 32*(2*(n)+4)); \
    ROWLD_S(CURS, WgC, 32*(2*(n)+5)); \
    SBAR();

#define FOR20(OP) \
    OP(0,  in,0,x, in,0,y, va,sa) \
    OP(1,  in,0,z, in,0,w, vb,sb) \
    OP(2,  in,1,x, in,1,y, va,sa) \
    OP(3,  in,1,z, in,1,w, vb,sb) \
    OP(4,  GS,0,x, GS,0,y, va,sa) \
    OP(5,  GS,0,z, GS,0,w, vb,sb) \
    OP(6,  GS,1,x, GS,1,y, va,sa) \
    OP(7,  GS,1,z, GS,1,w, vb,sb) \
    OP(8,  GS,2,x, GS,2,y, va,sa) \
    OP(9,  GS,2,z, GS,2,w, vb,sb) \
    OP(10, GS,3,x, GS,3,y, va,sa) \
    OP(11, GS,3,z, GS,3,w, vb,sb) \
    OP(12, GS,4,x, GS,4,y, va,sa) \
    OP(13, GS,4,z, GS,4,w, vb,sb) \
    OP(14, GS,5,x, GS,5,y, va,sa) \
    OP(15, GS,5,z, GS,5,w, vb,sb) \
    OP(16, GS,6,x, GS,6,y, va,sa) \
    OP(17, GS,6,z, GS,6,w, vb,sb) \
    OP(18, GS,7,x, GS,7,y, va,sa) \
    OP(19, GS,7,z, GS,7,w, vb,sb)

#define GATE_PIPE() \
    LDB(GP, WgL); \
    ROWLD_V(va, WgL, 0);  ROWLD_S(sa, WgC, 32); \
    ROWLD_V(vb, WgL, 64); ROWLD_S(sb, WgC, 96); SBAR(); \
    FOR20(STEP)

#define ZERO_OP(i,c,n) h##i.c = 0.0f; ac##i.c = 0.0f;
#define HR_OP(i,c,n)   o##i.c = sigm(o##i.c) * h##i.c;
#define TANH_OP(i,c,n) t##i.c = tanh_fast(t##i.c);
#define UPD_OP(i,c,n)  { float Zv = sigm(o##i.c); \
                         h##i.c = fmaf(Zv, h##i.c - t##i.c, t##i.c); \
                         ac##i.c = fmaf(pp, h##i.c, ac##i.c); }

#define OROW(a, ofs) do { \
    f4 u0 = CLD4(WO, (ofs)); \
    f4 u1 = CLD4(WO, (ofs) + 4); \
    f4 u2 = CLD4(WO, (ofs) + 8); \
    f4 u3 = CLD4(WO, (ofs) + 12); \
    f4 u4 = CLD4(WO, (ofs) + 16); \
    f4 u5 = CLD4(WO, (ofs) + 20); \
    float av = (a); \
    FMA4(q0, av, u0) FMA4(q1, av, u1) FMA4(q2, av, u2) \
    FMA4(q3, av, u3) FMA4(q4, av, u4) FMA4(q5, av, u5) \
    SBAR(); \
} while (0)

#define OUT_OP(i,c,n) OROW(fmaxf(ac##i.c, 0.0f), (n) * OUTF);

__global__ __launch_bounds__(64)
void k_gru(const float* __restrict__ AX, const float* __restrict__ wp,
           float* __restrict__ out) {
    __shared__ __align__(16) float sm[SM_TOT];
    int tid = threadIdx.x;
    // stage all packed params into LDS once (loop-invariant across periods)
    for (int i = tid; i < SM_TOT; i += 64) sm[i] = wp[i];
    __syncthreads();

    int g = blockIdx.x * 64 + tid;   // g = b*N + n
    if (g >= BN) return;

    f4 h0, h1, h2, h3, h4, h5, h6, h7;
    f4 ac0, ac1, ac2, ac3, ac4, ac5, ac6, ac7;
    f4 o0, o1, o2, o3, o4, o5, o6, o7;
    f4 t0, t1, t2, t3, t4, t5, t6, t7;
    f4 va0, va1, va2, va3, va4, va5, va6, va7;
    f4 vb0, vb1, vb2, vb3, vb4, vb5, vb6, vb7;
    f16v saL, saH, sbL, sbH;
    f4 in0, in1;
    FOR32(ZERO_OP)

    #pragma unroll 1
    for (int p = 0; p < PER; p++) {
        const float* axp = AX + (size_t)p * BN + g;
        in0.x = axp[0];
        in0.y = axp[(size_t)1 * PER * BN];
        in0.z = axp[(size_t)2 * PER * BN];
        in0.w = axp[(size_t)3 * PER * BN];
        in1.x = axp[(size_t)4 * PER * BN];
        in1.y = axp[(size_t)5 * PER * BN];
        in1.z = axp[(size_t)6 * PER * BN];
        in1.w = axp[(size_t)7 * PER * BN];
        float pp = sm[OFF_PROBS + p];

        // R gate: o = bias + M_r in + L_r H  (source h, target o)
        #define GP o
        #define GS h
        { const float* WgL = sm + OFF_WPK + GSTRIDE;
          const float* WgC = wp + OFF_WPK + GSTRIDE;
          GATE_PIPE() }
        #undef GP
        #undef GS
        FOR32(HR_OP)                      // o = sigm(o) * h

        // T gate: t = bias + M_h in + L_h (H*R)  (source o, target t)
        #define GP t
        #define GS o
        { const float* WgL = sm + OFF_WPK + 2 * GSTRIDE;
          const float* WgC = wp + OFF_WPK + 2 * GSTRIDE;
          GATE_PIPE() }
        #undef GP
        #undef GS
        FOR32(TANH_OP)

        // Z gate: o = bias + M_z in + L_z H  (source h, target o)
        #define GP o
        #define GS h
        { const float* WgL = sm + OFF_WPK;
          const float* WgC = wp + OFF_WPK;
          GATE_PIPE() }
        #undef GP
        #undef GS
        FOR32(UPD_OP)
    }

    // epilogue: relu(acc) @ Wout + bout  (constant-space, runs once)
    const float* WO = wp + OFF_WOUT;
    f4 q0 = CLD4(wp, OFF_BOUT + 0);
    f4 q1 = CLD4(wp, OFF_BOUT + 4);
    f4 q2 = CLD4(wp, OFF_BOUT + 8);
    f4 q3 = CLD4(wp, OFF_BOUT + 12);
    f4 q4 = CLD4(wp, OFF_BOUT + 16);
    f4 q5 = CLD4(wp, OFF_BOUT + 20);
    FOR32(OUT_OP)

    float* op = out + (size_t)g * OUTF;
    *(f4*)(op + 0)  = q0; *(f4*)(op + 4)  = q1;
    *(f4*)(op + 8)  = q2; *(f4*)(op + 12) = q3;
    *(f4*)(op + 16) = q4; *(f4*)(op + 20) = q5;
}

extern "C" void kernel_launch(void* const* d_in, const int* in_sizes, int n_in,
                              void* d_out, int out_size, void* d_ws, size_t ws_size,
                              hipStream_t stream) {
    if (ws_size < (size_t)WS_FLOATS * sizeof(float)) return;  // need ~45.6 MB scratch

    const float* x    = (const float*)d_in[0];
    const int*   ei   = (const int*)d_in[1];
    const float* att  = (const float*)d_in[2];
    const float* Wz   = (const float*)d_in[3];
    const float* bz   = (const float*)d_in[4];
    const float* Wr   = (const float*)d_in[5];
    const float* br   = (const float*)d_in[6];
    const float* Wh   = (const float*)d_in[7];
    const float* bh   = (const float*)d_in[8];
    const float* Lz   = (const float*)d_in[9];
    const float* lbz  = (const float*)d_in[10];
    const float* Lr   = (const float*)d_in[11];
    const float* lbr  = (const float*)d_in[12];
    const float* Lh   = (const float*)d_in[13];
    const float* lbh  = (const float*)d_in[14];
    const float* Wout = (const float*)d_in[15];
    const float* bout = (const float*)d_in[16];
    float* out = (float*)d_out;
    float* ws  = (float*)d_ws;

    const int* src = ei;
    const int* dst = ei + NE;

    float* dinv   = ws + OFF_DINV;
    int*   degi   = (int*)(ws + OFF_DEGI);
    int*   cursor = (int*)(ws + OFF_CURSOR);
    int*   rowptr = (int*)(ws + OFF_ROWPTR);
    int*   col    = (int*)(ws + OFF_COL);
    float* wgt    = ws + OFF_WGT;
    float* AX     = ws + OFF_AX;

    hipMemsetAsync(degi, 0, 2 * (size_t)NN * sizeof(int), stream);
    k_deg<<<(NE + 255) / 256, 256, 0, stream>>>(dst, degi);
    k_prep<<<1, 256, 0, stream>>>(att, Wz, bz, Wr, br, Wh, bh,
                                  Lz, lbz, Lr, lbr, Lh, lbh, Wout, bout, ws);
    k_scan<<<1, 1024, 0, stream>>>(degi, rowptr, dinv);
    k_csr<<<(NE + 255) / 256, 256, 0, stream>>>(src, dst, rowptr, cursor, dinv, col, wgt);
    dim3 gAgg((2 * NN + 255) / 256, 2);
    k_agg<<<gAgg, 256, 0, stream>>>(x, rowptr, col, wgt, dinv, AX);
    k_gru<<<(BN + 63) / 64, 64, 0, stream>>>(AX, ws, out);
}